// Round 7
// baseline (100.623 us; speedup 1.0000x reference)
//
#include <hip/hip_runtime.h>

// OIntInferMatMul: y = clip(round( (clip(round(x1*r1)) @ clip(round(x2*r2))) / 16 ), -128, 127)
// x1: [32, 2048, 64] fp32 (integer-valued), x2: [32, 64, 2048] fp32 -> out [32, 2048, 2048] fp32.
// Round 7: per-WAVE private slab slices (each wave's 64x64 quadrant is transpose-closed)
// -> ZERO __syncthreads -> no s_waitcnt vmcnt(0) drains of the NT store queue.
// Base: round 6 (B-prepack, in-reg A-quant, NT full-line stores).

typedef int   v4i  __attribute__((ext_vector_type(4)));
typedef int   v16i __attribute__((ext_vector_type(16)));
typedef float v4f  __attribute__((ext_vector_type(4)));

static constexpr int BATCH = 32;     // 2*16 fused batch-heads
static constexpr int SEQ   = 2048;
static constexpr int DIM   = 64;
static constexpr int TILE  = 128;
static constexpr int TPB   = 256;    // 4 waves, 2x2; each wave owns 64x64
static constexpr int TPS   = SEQ / TILE;          // 16
static constexpr int TPBATCH = TPS * TPS;         // 256
static constexpr int NBLK  = BATCH * TPBATCH;     // 8192
static constexpr size_t PKB = (size_t)BATCH * SEQ * DIM;   // 4 MiB packed B

__device__ __forceinline__ int qpack4(v4f v, float r) {
    int dw = 0;
    #pragma unroll
    for (int j = 0; j < 4; ++j) {
        float q = rintf(v[j] * r);           // round half-even == jnp.round
        q = fminf(fmaxf(q, -128.f), 127.f);  // clip
        dw |= ((int)q & 0xFF) << (8 * j);
    }
    return dw;
}

// B8 layout: [b][kq][n][16B], kq = k/16.
__global__ __launch_bounds__(256) void prepack_b_kernel(
    const float* __restrict__ x2,
    const float* __restrict__ p_s2ll, const float* __restrict__ p_sx2,
    char* __restrict__ B8)
{
    const float r2 = p_s2ll[0] / p_sx2[0];
    const int t  = (int)blockIdx.x * 256 + (int)threadIdx.x;   // [0, 256K)
    const int b  = t >> 13;
    const int kq = (t >> 11) & 3;
    const int n  = t & 2047;
    const float* src = x2 + (size_t)b * DIM * SEQ + (size_t)(kq * 16) * SEQ + n;
    v4i pk;
    #pragma unroll
    for (int d = 0; d < 4; ++d) {
        int dw = 0;
        #pragma unroll
        for (int j = 0; j < 4; ++j) {
            float q = rintf(src[(size_t)(4 * d + j) * SEQ] * r2);
            q = fminf(fmaxf(q, -128.f), 127.f);
            dw |= ((int)q & 0xFF) << (8 * j);
        }
        pk[d] = dw;
    }
    *(v4i*)(B8 + (size_t)t * 16) = pk;       // flat index == ((b*4+kq)*SEQ+n)
}

__global__ __launch_bounds__(TPB) void oint_mm_packed(
    const float* __restrict__ x1,
    const float* __restrict__ p_s1ll, const float* __restrict__ p_sx1,
    const char* __restrict__ B8,
    float* __restrict__ out)
{
    // Per-wave private 8 KiB transpose slices: 32 rows x 64 cols fp32 each.
    // No cross-wave LDS sharing anywhere -> no __syncthreads in the kernel.
    __shared__ float slab[TPB / 64][32 * 64];

    const float r1 = p_s1ll[0] / p_sx1[0];

    const int bid     = (int)blockIdx.x;
    const int logical = (bid & 7) * (NBLK >> 3) + (bid >> 3);   // bijective XCD swizzle

    const int batch = logical >> 8;
    const int t     = logical & (TPBATCH - 1);
    const int tm    = t >> 4;
    const int tn    = t & (TPS - 1);

    const float* Abase = x1 + (size_t)batch * SEQ * DIM;
    float*       Obase = out + (size_t)batch * SEQ * SEQ;

    const int tid  = (int)threadIdx.x;
    const int lane = tid & 63;
    const int wave = tid >> 6;
    const int wr   = wave >> 1;
    const int wc   = wave & 1;

    const int mbase = tm * TILE + wr * 64;
    const int nbase = tn * TILE + wc * 64;

    const int lc = lane & 31;   // row (A) / col (B, D) within 32x32 fragment
    const int kh = lane >> 5;   // k-half within a 32-wide MFMA step

    float* ws = slab[wave];

    // ---- B fragments: one dwordx4 each from packed B8 (wave-dense 512B segments) ----
    v4i bfrag[2][2];
    #pragma unroll
    for (int fn = 0; fn < 2; ++fn)
        #pragma unroll
        for (int s = 0; s < 2; ++s)
            bfrag[fn][s] = *(const v4i*)(
                B8 + ((size_t)(batch * 4 + s * 2 + kh) * SEQ + nbase + fn * 32 + lc) * 16);

    #pragma unroll
    for (int fm = 0; fm < 2; ++fm) {
        // ---- A fragments: quantize in-register from contiguous fp32 (L3-resident) ----
        v4i af[2];
        #pragma unroll
        for (int s = 0; s < 2; ++s) {
            const float* src = Abase + (size_t)(mbase + fm * 32 + lc) * DIM + s * 32 + kh * 16;
            v4i pk;
            #pragma unroll
            for (int d = 0; d < 4; ++d) pk[d] = qpack4(*(const v4f*)(src + 4 * d), r1);
            af[s] = pk;
        }

        // ---- MFMA + epilogue math -> this wave's private slab slice ----
        #pragma unroll
        for (int fn = 0; fn < 2; ++fn) {
            v16i z = {0,0,0,0,0,0,0,0,0,0,0,0,0,0,0,0};
            v16i acc = __builtin_amdgcn_mfma_i32_32x32x32_i8(af[0], bfrag[fn][0], z,   0, 0, 0);
            acc      = __builtin_amdgcn_mfma_i32_32x32x32_i8(af[1], bfrag[fn][1], acc, 0, 0, 0);

            // D layout (32x32): col = lane&31, row = (r&3) + 8*(r>>2) + 4*kh.
            #pragma unroll
            for (int r = 0; r < 16; ++r) {
                const int rloc = (r & 3) + 8 * (r >> 2) + 4 * kh;      // [0,32)
                float v = rintf((float)acc[r] * 0.0625f);   // exact: |acc| <= 2^20
                v = fminf(fmaxf(v, -128.f), 127.f);
                ws[rloc * 64 + fn * 32 + lc] = v;   // lane pairs (l, l+32) alias -> 2-way, free
            }
        }

        // ---- In-wave transposed read + NT store (lgkmcnt orders ds ops; no barrier) ----
        // 32 rows x 64 cols: instr i covers rows 4i..4i+3, 256B contiguous per row.
        #pragma unroll
        for (int i = 0; i < 8; ++i) {
            const int f = i * 64 + lane;
            const int r = f >> 4;                 // [0,32)
            const int q = f & 15;                 // float4 index within row
            v4f v = *(const v4f*)&ws[r * 64 + q * 4];
            const int grow = mbase + fm * 32 + r;
            __builtin_nontemporal_store(
                v, (v4f*)(Obase + (size_t)grow * SEQ + nbase + q * 4));
        }
    }
}

extern "C" void kernel_launch(void* const* d_in, const int* in_sizes, int n_in,
                              void* d_out, int out_size, void* d_ws, size_t ws_size,
                              hipStream_t stream) {
    (void)in_sizes; (void)n_in; (void)out_size; (void)ws_size;
    const float* x1 = (const float*)d_in[0];
    const float* x2 = (const float*)d_in[1];
    const float* s1 = (const float*)d_in[2];
    const float* s2 = (const float*)d_in[3];
    const float* s3 = (const float*)d_in[4];
    const float* s4 = (const float*)d_in[5];
    float* out = (float*)d_out;

    char* B8 = (char*)d_ws;
    prepack_b_kernel<<<1024, 256, 0, stream>>>(x2, s3, s4, B8);
    oint_mm_packed<<<NBLK, TPB, 0, stream>>>(x1, s1, s2, B8, out);
}

// Round 8
// 96.334 us; speedup vs baseline: 1.0445x; 1.0445x over previous
//
#include <hip/hip_runtime.h>

// OIntInferMatMul: y = clip(round( (clip(round(x1*r1)) @ clip(round(x2*r2))) / 16 ), -128, 127)
// x1: [32, 2048, 64] fp32 (integer-valued), x2: [32, 64, 2048] fp32 -> out [32, 2048, 2048] fp32.
// Round 8: round-6 base (best, 96.2us) with 64x256 tile (was 128x128): every store
// instruction now covers ONE FULL 1KB contiguous row segment (was 2x512B) -> 2x DRAM
// page locality on the write stream. Same TPB/NBLK/slab-size/barrier structure.

typedef int   v4i  __attribute__((ext_vector_type(4)));
typedef int   v16i __attribute__((ext_vector_type(16)));
typedef float v4f  __attribute__((ext_vector_type(4)));

static constexpr int BATCH = 32;     // 2*16 fused batch-heads
static constexpr int SEQ   = 2048;
static constexpr int DIM   = 64;
static constexpr int TM    = 64;     // tile rows
static constexpr int TN    = 256;    // tile cols (1KB fp32 per row segment)
static constexpr int TPB   = 256;    // 4 waves, 1x4 grid; each wave 64x64
static constexpr int TPSM  = SEQ / TM;            // 32
static constexpr int TPSN  = SEQ / TN;            // 8
static constexpr int TPBATCH = TPSM * TPSN;       // 256
static constexpr int NBLK  = BATCH * TPBATCH;     // 8192
static constexpr size_t PKB = (size_t)BATCH * SEQ * DIM;   // 4 MiB packed B

__device__ __forceinline__ int qpack4(v4f v, float r) {
    int dw = 0;
    #pragma unroll
    for (int j = 0; j < 4; ++j) {
        float q = rintf(v[j] * r);           // round half-even == jnp.round
        q = fminf(fmaxf(q, -128.f), 127.f);  // clip
        dw |= ((int)q & 0xFF) << (8 * j);
    }
    return dw;
}

// B8 layout: [b][kq][n][16B], kq = k/16.
__global__ __launch_bounds__(256) void prepack_b_kernel(
    const float* __restrict__ x2,
    const float* __restrict__ p_s2ll, const float* __restrict__ p_sx2,
    char* __restrict__ B8)
{
    const float r2 = p_s2ll[0] / p_sx2[0];
    const int t  = (int)blockIdx.x * 256 + (int)threadIdx.x;   // [0, 256K)
    const int b  = t >> 13;
    const int kq = (t >> 11) & 3;
    const int n  = t & 2047;
    const float* src = x2 + (size_t)b * DIM * SEQ + (size_t)(kq * 16) * SEQ + n;
    v4i pk;
    #pragma unroll
    for (int d = 0; d < 4; ++d) {
        int dw = 0;
        #pragma unroll
        for (int j = 0; j < 4; ++j) {
            float q = rintf(src[(size_t)(4 * d + j) * SEQ] * r2);
            q = fminf(fmaxf(q, -128.f), 127.f);
            dw |= ((int)q & 0xFF) << (8 * j);
        }
        pk[d] = dw;
    }
    *(v4i*)(B8 + (size_t)t * 16) = pk;       // flat index == ((b*4+kq)*SEQ+n)
}

__global__ __launch_bounds__(TPB) void oint_mm_packed(
    const float* __restrict__ x1,
    const float* __restrict__ p_s1ll, const float* __restrict__ p_sx1,
    const char* __restrict__ B8,
    float* __restrict__ out)
{
    __shared__ float slab[32 * 256];   // 32 KiB: one 32-row x 256-col phase

    const float r1 = p_s1ll[0] / p_sx1[0];

    const int bid     = (int)blockIdx.x;
    const int logical = (bid & 7) * (NBLK >> 3) + (bid >> 3);   // bijective XCD swizzle

    const int batch = logical >> 8;
    const int t     = logical & (TPBATCH - 1);
    const int tm    = t >> 3;                 // [0,32)
    const int tn    = t & (TPSN - 1);         // [0,8)

    const float* Abase = x1 + (size_t)batch * SEQ * DIM;
    float*       Obase = out + (size_t)batch * SEQ * SEQ;

    const int tid  = (int)threadIdx.x;
    const int lane = tid & 63;
    const int wave = tid >> 6;                // 1x4 wave grid: wave = col quadrant

    const int mbase = tm * TM;                // all waves share the same 64 rows
    const int nbase = tn * TN + wave * 64;

    const int lc = lane & 31;   // row (A) / col (B, D) within 32x32 fragment
    const int kh = lane >> 5;   // k-half within a 32-wide MFMA step

    // ---- B fragments: one dwordx4 each from packed B8 (wave-dense 512B segments) ----
    v4i bfrag[2][2];
    #pragma unroll
    for (int fn = 0; fn < 2; ++fn)
        #pragma unroll
        for (int s = 0; s < 2; ++s)
            bfrag[fn][s] = *(const v4i*)(
                B8 + ((size_t)(batch * 4 + s * 2 + kh) * SEQ + nbase + fn * 32 + lc) * 16);

    #pragma unroll
    for (int fm = 0; fm < 2; ++fm) {
        if (fm) __syncthreads();   // slab reuse guard between phases

        // ---- A fragments: quantize in-register from contiguous fp32 (L2-resident) ----
        v4i af[2];
        #pragma unroll
        for (int s = 0; s < 2; ++s) {
            const float* src = Abase + (size_t)(mbase + fm * 32 + lc) * DIM + s * 32 + kh * 16;
            v4i pk;
            #pragma unroll
            for (int d = 0; d < 4; ++d) pk[d] = qpack4(*(const v4f*)(src + 4 * d), r1);
            af[s] = pk;
        }

        // ---- MFMA + epilogue math -> slab (32 rows x 256 cols fp32) ----
        #pragma unroll
        for (int fn = 0; fn < 2; ++fn) {
            v16i z = {0,0,0,0,0,0,0,0,0,0,0,0,0,0,0,0};
            v16i acc = __builtin_amdgcn_mfma_i32_32x32x32_i8(af[0], bfrag[fn][0], z,   0, 0, 0);
            acc      = __builtin_amdgcn_mfma_i32_32x32x32_i8(af[1], bfrag[fn][1], acc, 0, 0, 0);

            // D layout (32x32): col = lane&31, row = (r&3) + 8*(r>>2) + 4*kh.
            #pragma unroll
            for (int r = 0; r < 16; ++r) {
                const int rloc = (r & 3) + 8 * (r >> 2) + 4 * kh;      // [0,32)
                const int c    = wave * 64 + fn * 32 + lc;             // [0,256)
                float v = rintf((float)acc[r] * 0.0625f);   // exact: |acc| <= 2^20
                v = fminf(fmaxf(v, -128.f), 127.f);
                slab[rloc * 256 + c] = v;   // 2-way bank alias only (free)
            }
        }

        __syncthreads();

        // ---- Cooperative store: each wave-instr = ONE row's 1KB contiguous NT burst ----
        #pragma unroll
        for (int i = 0; i < 8; ++i) {
            const int f = i * TPB + tid;          // [0, 2048) float4 index
            const int r = f >> 6;                 // slab row [0,32)
            const int q = f & 63;                 // float4 within row
            v4f v = *(const v4f*)&slab[r * 256 + q * 4];
            const int grow = mbase + fm * 32 + r;
            __builtin_nontemporal_store(
                v, (v4f*)(Obase + (size_t)grow * SEQ + tn * TN + q * 4));
        }
    }
}

extern "C" void kernel_launch(void* const* d_in, const int* in_sizes, int n_in,
                              void* d_out, int out_size, void* d_ws, size_t ws_size,
                              hipStream_t stream) {
    (void)in_sizes; (void)n_in; (void)out_size; (void)ws_size;
    const float* x1 = (const float*)d_in[0];
    const float* x2 = (const float*)d_in[1];
    const float* s1 = (const float*)d_in[2];
    const float* s2 = (const float*)d_in[3];
    const float* s3 = (const float*)d_in[4];
    const float* s4 = (const float*)d_in[5];
    float* out = (float*)d_out;

    char* B8 = (char*)d_ws;
    prepack_b_kernel<<<1024, 256, 0, stream>>>(x2, s3, s4, B8);
    oint_mm_packed<<<NBLK, TPB, 0, stream>>>(x1, s1, s2, B8, out);
}